// Round 3
// baseline (2656.213 us; speedup 1.0000x reference)
//
#include <hip/hip_runtime.h>

#define NPTS 8192
#define SPTS 2048
#define KS 32
#define CF 64
#define BQ 4
#define FPS_T 512
#define PPT 16               // points per thread
#define NPAIR 8              // PPT/2, packed-f32 pairs
#define FPS_SHIFT 9          // log2(FPS_T)

#define OFF_GROUPED 24576                    // B*S*3
#define GROUPED_SZ  17563648                 // B*67*S*K
#define OFF_FPSIDX  (OFF_GROUPED + GROUPED_SZ)

typedef __attribute__((ext_vector_type(2))) float vf2;
typedef unsigned long long u64;

// ---------------- FPS: one block per batch, 1 barrier per iteration ----------------
__global__ __launch_bounds__(FPS_T, 2)
void fps_kernel(const float* __restrict__ xyz, float* __restrict__ out)
{
#pragma clang fp contract(off)
    __shared__ u64 slots[2][8];          // parity double-buffer; one slot per wave
    const int b    = blockIdx.x;
    const int tid  = threadIdx.x;
    const int wv   = tid >> 6;
    const int lane = tid & 63;
    const float* xb = xyz + (size_t)b * (NPTS * 3);

    // SoA packed pairs: pair h holds points j=2h (.x) and j=2h+1 (.y),
    // global index of (t, j) is t + (j << FPS_SHIFT)
    vf2 px[NPAIR], py[NPAIR], pz[NPAIR], mdp[NPAIR];
#pragma unroll
    for (int h = 0; h < NPAIR; ++h) {
        const int p0 = tid + ((2 * h) << FPS_SHIFT);
        const int p1 = p0 + FPS_T;
        float x0 = xb[p0 * 3 + 0], y0 = xb[p0 * 3 + 1], z0 = xb[p0 * 3 + 2];
        float x1 = xb[p1 * 3 + 0], y1 = xb[p1 * 3 + 1], z1 = xb[p1 * 3 + 2];
        // pin in VGPRs: forbid rematerialization-from-global inside the loop
        asm volatile("" : "+v"(x0), "+v"(y0), "+v"(z0), "+v"(x1), "+v"(y1), "+v"(z1));
        px[h].x = x0; px[h].y = x1;
        py[h].x = y0; py[h].y = y1;
        pz[h].x = z0; pz[h].y = z1;
        mdp[h].x = 1e10f; mdp[h].y = 1e10f;
    }

    float* newxyz = out;
    float* fpsidx = out + OFF_FPSIDX;

    // iteration 0: center = point 0
    float qx = xb[0], qy = xb[1], qz = xb[2];
    if (tid == 0) {
        fpsidx[(size_t)b * SPTS + 0] = 0.0f;
        newxyz[(size_t)b * SPTS * 3 + 0] = qx;
        newxyz[(size_t)b * SPTS * 3 + 1] = qy;
        newxyz[(size_t)b * SPTS * 3 + 2] = qz;
    }

    for (int i = 1; i < SPTS; ++i) {
        vf2 q2x; q2x.x = qx; q2x.y = qx;
        vf2 q2y; q2y.x = qy; q2y.y = qy;
        vf2 q2z; q2z.x = qz; q2z.y = qz;

        // packed min-dist update: exact numpy order (dx*dx+dy*dy)+dz*dz, no fma
#pragma unroll
        for (int h = 0; h < NPAIR; ++h) {
            const vf2 dx = px[h] - q2x;          // v_pk_add_f32 (neg)
            const vf2 dy = py[h] - q2y;
            const vf2 dz = pz[h] - q2z;
            const vf2 sx = dx * dx;              // v_pk_mul_f32
            const vf2 sy = dy * dy;
            const vf2 sz = dz * dz;
            const vf2 t  = sx + sy;              // v_pk_add_f32
            const vf2 d  = t + sz;
            mdp[h].x = fminf(mdp[h].x, d.x);
            mdp[h].y = fminf(mdp[h].y, d.y);
        }

        // max tree over 16 components
        float a0 = fmaxf(mdp[0].x, mdp[0].y), a1 = fmaxf(mdp[1].x, mdp[1].y);
        float a2 = fmaxf(mdp[2].x, mdp[2].y), a3 = fmaxf(mdp[3].x, mdp[3].y);
        float a4 = fmaxf(mdp[4].x, mdp[4].y), a5 = fmaxf(mdp[5].x, mdp[5].y);
        float a6 = fmaxf(mdp[6].x, mdp[6].y), a7 = fmaxf(mdp[7].x, mdp[7].y);
        a0 = fmaxf(a0, a1); a2 = fmaxf(a2, a3); a4 = fmaxf(a4, a5); a6 = fmaxf(a6, a7);
        a0 = fmaxf(a0, a2); a4 = fmaxf(a4, a6);
        const float best = fmaxf(a0, a4);

        // smallest owned j with md==best (descending overwrite -> first max)
        int bj = PPT - 1;
#pragma unroll
        for (int j = PPT - 2; j >= 0; --j) {
            const float v = (j & 1) ? mdp[j >> 1].y : mdp[j >> 1].x;
            if (v == best) bj = j;
        }
        const int bidx = tid + (bj << FPS_SHIFT);

        // wave argmax: f32 butterfly (cheap 32-bit shuffles), then ballot+readlane
        float wmax = best;
#pragma unroll
        for (int off = 32; off > 0; off >>= 1)
            wmax = fmaxf(wmax, __shfl_xor(wmax, off));

        const u64 m = __ballot(best == wmax);
        int widx_w;
        if (__popcll(m) == 1) {                  // wave-uniform branch, common case
            const int lane1 = __ffsll((long long)m) - 1;
            widx_w = __builtin_amdgcn_readlane(bidx, lane1);
        } else {                                 // exact dist tie: min index wins
            int cand = (best == wmax) ? bidx : 0x7FFFFFFF;
#pragma unroll
            for (int off = 32; off > 0; off >>= 1)
                cand = min(cand, __shfl_xor(cand, off));
            widx_w = cand;
        }

        if (lane == 0) {
            slots[i & 1][wv] = ((u64)__float_as_uint(wmax) << 32) |
                               (unsigned)(NPTS - 1 - widx_w);
        }
        __syncthreads();                         // the only barrier per iteration

        // cross-wave reduce: 8 broadcast LDS u64 reads + compare tree
        u64 s0 = slots[i & 1][0], s1 = slots[i & 1][1];
        u64 s2 = slots[i & 1][2], s3 = slots[i & 1][3];
        u64 s4 = slots[i & 1][4], s5 = slots[i & 1][5];
        u64 s6 = slots[i & 1][6], s7 = slots[i & 1][7];
        s0 = s0 > s1 ? s0 : s1;  s2 = s2 > s3 ? s2 : s3;
        s4 = s4 > s5 ? s4 : s5;  s6 = s6 > s7 ? s6 : s7;
        s0 = s0 > s2 ? s0 : s2;  s4 = s4 > s6 ? s4 : s6;
        const u64 g = s0 > s4 ? s0 : s4;
        const int widx = (NPTS - 1) - (int)(unsigned)(g & 0xffffffffull);

        // winner coords: broadcast load from global (L2-hot), no 2nd barrier
        qx = xb[widx * 3 + 0];
        qy = xb[widx * 3 + 1];
        qz = xb[widx * 3 + 2];

        if (tid == 0) {
            fpsidx[(size_t)b * SPTS + i] = (float)widx;
            const size_t o = ((size_t)b * SPTS + i) * 3;
            newxyz[o + 0] = qx; newxyz[o + 1] = qy; newxyz[o + 2] = qz;
        }
    }
}

// ---------------- ball query + grouping: one wave per center ----------------
__global__ __launch_bounds__(256)
void ballgroup_kernel(const float* __restrict__ xyz, const float* __restrict__ feat,
                      float* out)
{
#pragma clang fp contract(off)
    __shared__ int idxl[4][KS];
    const int tid    = threadIdx.x;
    const int wv     = tid >> 6;
    const int lane   = tid & 63;
    const int center = blockIdx.x * 4 + wv;
    const int b      = center >> 11;          // / SPTS
    const int s      = center & (SPTS - 1);
    const float* xb  = xyz + (size_t)b * (NPTS * 3);
    const float* newxyz = out;                // written by fps_kernel earlier in stream
    const float cx = newxyz[(size_t)center * 3 + 0];
    const float cy = newxyz[(size_t)center * 3 + 1];
    const float cz = newxyz[(size_t)center * 3 + 2];

    if (lane == 0) idxl[wv][0] = 0;           // default when zero hits

    int cnt = 0;
    for (int nb = 0; nb < NPTS; nb += 64) {
        const int p = nb + lane;
        const float x = xb[p * 3 + 0];
        const float y = xb[p * 3 + 1];
        const float z = xb[p * 3 + 2];
        const float dx = cx - x, dy = cy - y, dz = cz - z;
        const float d2 = (dx * dx + dy * dy) + dz * dz;
        // f32 'd2 <= 0.04f' == numpy 'f32 d2 < float64(0.2*0.2)'
        const bool in = (d2 <= 0.04f);
        const unsigned long long mk = __ballot(in);
        if (in) {
            const int pos = cnt + __popcll(mk & ((1ull << lane) - 1ull));
            if (pos < KS) idxl[wv][pos] = p;
        }
        cnt += (int)__popcll(mk);
        if (cnt >= KS) break;                 // cnt is wave-uniform
    }
    const int cc = cnt < KS ? cnt : KS;

    // pad short lists with first hit (or 0), write padded list back
    int myidx = 0;
    if (lane < KS) {
        myidx = (lane < cc) ? idxl[wv][lane] : idxl[wv][0];
        idxl[wv][lane] = myidx;
    }

    float* grouped = out + OFF_GROUPED;
    const size_t chstride = (size_t)SPTS * KS;                    // 65536
    const size_t base67   = (size_t)b * 67 * chstride + (size_t)s * KS;

    // channels 0..2: recentered coords (point - center)
    if (lane < KS) {
        const float gx = xb[(size_t)myidx * 3 + 0] - cx;
        const float gy = xb[(size_t)myidx * 3 + 1] - cy;
        const float gz = xb[(size_t)myidx * 3 + 2] - cz;
        grouped[base67 + 0 * chstride + lane] = gx;
        grouped[base67 + 1 * chstride + lane] = gy;
        grouped[base67 + 2 * chstride + lane] = gz;
    }

    // channels 3..66: feature gather; lanes = (k, c-half)
    const int k    = lane & (KS - 1);
    const int half = lane >> 5;
    const int gi   = idxl[wv][k];
    const float* fb = feat + (size_t)b * CF * NPTS;
    const size_t obase = base67 + 3 * chstride + (size_t)k;
#pragma unroll 8
    for (int c0 = 0; c0 < 32; ++c0) {
        const int c = c0 * 2 + half;
        grouped[obase + (size_t)c * chstride] = fb[(size_t)c * NPTS + gi];
    }
}

extern "C" void kernel_launch(void* const* d_in, const int* in_sizes, int n_in,
                              void* d_out, int out_size, void* d_ws, size_t ws_size,
                              hipStream_t stream) {
    const float* xyz  = (const float*)d_in[0];
    const float* feat = (const float*)d_in[1];
    float* out = (float*)d_out;
    fps_kernel<<<dim3(BQ), dim3(FPS_T), 0, stream>>>(xyz, out);
    ballgroup_kernel<<<dim3((BQ * SPTS) / 4), dim3(256), 0, stream>>>(xyz, feat, out);
}